// Round 4
// baseline (233.430 us; speedup 1.0000x reference)
//
#include <hip/hip_runtime.h>
#include <cmath>

#define GAS __attribute__((address_space(1)))
#define LAS __attribute__((address_space(3)))

typedef __bf16 bf16x8 __attribute__((ext_vector_type(8)));
typedef float f32x4 __attribute__((ext_vector_type(4)));

__device__ __forceinline__ void gload16(const void* g, void* l) {
    __builtin_amdgcn_global_load_lds((const GAS void*)g, (LAS void*)l, 16, 0, 0);
}

// ---------------- merged fp32 -> bf16 converts (8 elems / thread) ----------------
__global__ void k_prep_convert(const float* __restrict__ gnn, const float* __restrict__ tr,
                               const float* __restrict__ Wo, const float* __restrict__ W1,
                               const float* __restrict__ W2, const float* __restrict__ Wg,
                               const float* __restrict__ Wt,
                               __bf16* __restrict__ X, __bf16* __restrict__ Wo_b,
                               __bf16* __restrict__ W1ab, __bf16* __restrict__ Wp) {
    int b = blockIdx.x;
    const float* src; __bf16* dst; int sld, dld, base, c8;
    if (b < 4096)       { src = gnn;       sld = 512;  dst = X + 1024;        dld = 2304; base = 0;     c8 = 64; }
    else if (b < 10240) { src = tr;        sld = 768;  dst = X + 1536;        dld = 2304; base = 4096;  c8 = 96; }
    else if (b < 10752) { src = Wo;        sld = 1024; dst = Wo_b;            dld = 1024; base = 10240; c8 = 128; }
    else if (b < 11264) { src = W1;        sld = 2048; dst = W1ab;            dld = 1024; base = 10752; c8 = 128; }
    else if (b < 11776) { src = W1 + 1024; sld = 2048; dst = W1ab + 1024*1024; dld = 1024; base = 11264; c8 = 128; }
    else if (b < 12288) { src = W2;        sld = 1024; dst = Wp;              dld = 2304; base = 11776; c8 = 128; }
    else if (b < 12544) { src = Wg;        sld = 512;  dst = Wp + 1024;       dld = 2304; base = 12288; c8 = 64; }
    else                { src = Wt;        sld = 768;  dst = Wp + 1536;       dld = 2304; base = 12544; c8 = 96; }
    int idx = (b - base) * 256 + threadIdx.x;
    int r = idx / c8;
    int c = (idx - r * c8) << 3;
    const float4* s = reinterpret_cast<const float4*>(src + (long)r * sld + c);
    float4 x0 = s[0], x1 = s[1];
    bf16x8 v;
    v[0] = (__bf16)x0.x; v[1] = (__bf16)x0.y; v[2] = (__bf16)x0.z; v[3] = (__bf16)x0.w;
    v[4] = (__bf16)x1.x; v[5] = (__bf16)x1.y; v[6] = (__bf16)x1.z; v[7] = (__bf16)x1.w;
    *reinterpret_cast<bf16x8*>(dst + (long)r * dld + c) = v;
}

// ---------------- merged fp32 [R][C] -> bf16 [C][R] transposes ----------------
__global__ void k_prep_transpose(const float* __restrict__ Wv, const float* __restrict__ Wg,
                                 const float* __restrict__ Wt,
                                 __bf16* __restrict__ WvT, __bf16* __restrict__ WgT,
                                 __bf16* __restrict__ WtT) {
    __shared__ float t[32][33];
    int b = blockIdx.x;
    const float* src; __bf16* dst; int R, C, tile;
    if (b < 1024)      { src = Wv; dst = WvT; R = 1024; C = 1024; tile = b; }
    else if (b < 1536) { src = Wg; dst = WgT; R = 1024; C = 512;  tile = b - 1024; }
    else               { src = Wt; dst = WtT; R = 1024; C = 768;  tile = b - 1536; }
    int tx_n = C >> 5;
    int c0 = (tile % tx_n) << 5, r0 = (tile / tx_n) << 5;
    int tx = threadIdx.x, ty = threadIdx.y;  // 32 x 8
    #pragma unroll
    for (int i = 0; i < 32; i += 8)
        t[ty + i][tx] = src[(long)(r0 + ty + i) * C + c0 + tx];
    __syncthreads();
    #pragma unroll
    for (int i = 0; i < 32; i += 8)
        dst[(long)(c0 + ty + i) * R + r0 + tx] = (__bf16)t[tx][ty + i];
}

// ---------------- bias helpers ----------------
__global__ void k_bias_att(const float* __restrict__ Wo, const float* __restrict__ bv,
                           const float* __restrict__ bo, float* __restrict__ b_att) {
    int i = blockIdx.x;
    float s = 0.f;
    for (int k = threadIdx.x; k < 1024; k += 256) s += Wo[i * 1024 + k] * bv[k];
    __shared__ float red[256];
    red[threadIdx.x] = s;
    __syncthreads();
    for (int off = 128; off > 0; off >>= 1) {
        if (threadIdx.x < off) red[threadIdx.x] += red[threadIdx.x + off];
        __syncthreads();
    }
    if (threadIdx.x == 0) b_att[i] = red[0] + bo[i];
}

__global__ void k_bias_z2(const float* __restrict__ W1, const float* __restrict__ b_att,
                          const float* __restrict__ b1,
                          const __bf16* __restrict__ P, const __bf16* __restrict__ Q,
                          const float* __restrict__ bt, const float* __restrict__ bg,
                          const float* __restrict__ b2,
                          float* __restrict__ bz2, float* __restrict__ b_out) {
    int i = blockIdx.x;
    float s = 0.f;
    for (int k = threadIdx.x; k < 1024; k += 256) {
        s += (W1[(long)i * 2048 + k] + W1[(long)i * 2048 + 1024 + k]) * b_att[k];
        s += (float)P[i * 1024 + k] * bt[k];
        s += (float)Q[i * 1024 + k] * bg[k];
    }
    __shared__ float red[256];
    red[threadIdx.x] = s;
    __syncthreads();
    for (int off = 128; off > 0; off >>= 1) {
        if (threadIdx.x < off) red[threadIdx.x] += red[threadIdx.x + off];
        __syncthreads();
    }
    if (threadIdx.x == 0) {
        bz2[i] = red[0] + b1[i];
        b_out[i] = b2[i] + bg[i] + bt[i];
    }
}

// ---------------- small NT GEMM (64x64 tiles, 2-phase, verified) ----------------
template <int BM, int BN>
__global__ __launch_bounds__(256, 2) void k_gemm_nt(
    const __bf16* __restrict__ A, int lda,
    const __bf16* __restrict__ B, int ldb,
    __bf16* __restrict__ C, int ldc,
    int K, int n_tiles) {
    constexpr int BK = 32;
    constexpr int MR = BM / 32, NR = BN / 32;
    __shared__ alignas(16) __bf16 As[2][BM][BK];
    __shared__ alignas(16) __bf16 Bs[2][BN][BK];

    const int tid = threadIdx.x;
    const int lane = tid & 63;
    const int wave = tid >> 6;
    int bid = blockIdx.x;
    const int nwg = gridDim.x;
    if ((nwg & 7) == 0) bid = (bid & 7) * (nwg >> 3) + (bid >> 3);
    const int bn = bid % n_tiles;
    const int bm = bid / n_tiles;
    const int m0 = bm * BM, n0 = bn * BN;

    const int rp_l = tid >> 2;
    const int sp = tid & 3;

    const int wr = (wave >> 1) * (BM / 2);
    const int wc = (wave & 1) * (BN / 2);
    const int fr = lane & 15;
    const int fb = (lane >> 4) << 4;

    f32x4 acc[MR][NR] = {};
    const int nk = K / BK;

    auto stage = [&](int buf, int kt) {
        char* abase = (char*)&As[buf][0][0];
        char* bbase = (char*)&Bs[buf][0][0];
        #pragma unroll
        for (int it = 0; it < BM / 64; ++it) {
            int rp = it * 64 + rp_l;
            int rl = (rp & ~1) | ((rp ^ (rp >> 2)) & 1);
            int sl = sp ^ (rl & 3);
            gload16(A + (long)(m0 + rl) * lda + kt * BK + sl * 8,
                    abase + it * 4096 + tid * 16);
        }
        #pragma unroll
        for (int it = 0; it < BN / 64; ++it) {
            int rp = it * 64 + rp_l;
            int rl = (rp & ~1) | ((rp ^ (rp >> 2)) & 1);
            int sl = sp ^ (rl & 3);
            gload16(B + (long)(n0 + rl) * ldb + kt * BK + sl * 8,
                    bbase + it * 4096 + tid * 16);
        }
    };

    stage(0, 0);
    for (int kt = 0; kt < nk; ++kt) {
        const int buf = kt & 1;
        __syncthreads();
        if (kt + 1 < nk) stage(buf ^ 1, kt + 1);
        const char* abase = (const char*)&As[buf][0][0];
        const char* bbase = (const char*)&Bs[buf][0][0];
        bf16x8 af[MR], bfr[NR];
        #pragma unroll
        for (int m = 0; m < MR; ++m) {
            int r = wr + m * 16 + fr;
            af[m] = *(const bf16x8*)(abase + (((r << 6) + fb) ^ ((r & 7) << 4)));
        }
        #pragma unroll
        for (int n = 0; n < NR; ++n) {
            int r = wc + n * 16 + fr;
            bfr[n] = *(const bf16x8*)(bbase + (((r << 6) + fb) ^ ((r & 7) << 4)));
        }
        #pragma unroll
        for (int m = 0; m < MR; ++m)
            #pragma unroll
            for (int n = 0; n < NR; ++n)
                acc[m][n] = __builtin_amdgcn_mfma_f32_16x16x32_bf16(af[m], bfr[n], acc[m][n], 0, 0, 0);
    }

    const int r0 = (lane >> 4) << 2;
    #pragma unroll
    for (int n = 0; n < NR; ++n) {
        const int gc = n0 + wc + n * 16 + fr;
        #pragma unroll
        for (int m = 0; m < MR; ++m) {
            const long rbase = (long)(m0 + wr + m * 16 + r0);
            #pragma unroll
            for (int r = 0; r < 4; ++r)
                C[(rbase + r) * ldc + gc] = (__bf16)acc[m][n][r];
        }
    }
}

// ------------- 8-phase 256x256 NT GEMM, register read-ahead pipeline ------------
// Phase = {stage; [counted vmcnt]; barrier; RA ds_reads (frags for NEXT phase);
//          setprio; 16 MFMA on PREVIOUS phase's frags; setprio; barrier}.
// RA reads overlap the MFMA window in the LDS pipe; MFMA's lgkmcnt dependency is
// on reads issued a full phase earlier. Hazard ledger (vmcnt(4) at P4/P8):
// every RA target is drained by the preceding VMC+barrier; every stage that
// overwrites an RA-read region is >=2 phases later (fenced by barrier#2).
// MODE 1: +bias, GELU (tanh-form), bf16 out; MODE 2: +bias, fp32 out.
template <int MODE>
__global__ __launch_bounds__(512, 2) void k_gemm8(
    const __bf16* __restrict__ A, int lda,
    const __bf16* __restrict__ B, int ldb,
    void* __restrict__ Cv, int ldc,
    const float* __restrict__ bias,
    int K, int n_tiles) {
    __shared__ __bf16 As[2][2][256][32];
    __shared__ __bf16 Bs[2][2][256][32];

    const int tid = threadIdx.x;
    const int lane = tid & 63;
    const int wave = tid >> 6;
    const int wm = wave >> 2;   // 0..1 -> 128 M-rows
    const int wn = wave & 3;    // 0..3 -> 64 N-cols

    int bid = blockIdx.x;
    const int nwg = gridDim.x;
    if ((nwg & 7) == 0) bid = (bid & 7) * (nwg >> 3) + (bid >> 3);
    const int bn = bid % n_tiles;
    const int bm = bid / n_tiles;
    const int m0 = bm * 256, n0 = bn * 256;

    // staging precompute (inverse swizzle, r2-verified)
    const int rp0 = tid >> 2;                              // 0..127
    const int rl0 = (rp0 & ~1) | ((rp0 ^ (rp0 >> 2)) & 1); // logical row
    const int slo = (tid & 3) ^ (rl0 & 3);                 // logical 16B slot
    const __bf16* Ag = A + (long)(m0 + rl0) * lda + slo * 8;
    const __bf16* Bg = B + (long)(n0 + rl0) * ldb + slo * 8;
    const long lda128 = (long)128 * lda;
    const long ldb128 = (long)128 * ldb;
    const int tid16 = tid * 16;

    const int fr = lane & 15;
    const int gb = (lane >> 4) << 4;

    f32x4 acc[8][4] = {};
    bf16x8 af[2][4];    // A-frag double buffer (literal indices -> registers)
    bf16x8 bfr[2][4];   // B-frag double buffer

    const int nk = K >> 6;
    const int NI = nk >> 1;

#define STAGE_A(PAR, KT, KH) { \
        char* l_ = (char*)&As[PAR][KH][0][0] + tid16; \
        const __bf16* g_ = Ag + (long)(KT) * 64 + (KH) * 32; \
        gload16(g_, l_); \
        gload16(g_ + lda128, l_ + 8192); }
#define STAGE_B(PAR, KT, KH) { \
        char* l_ = (char*)&Bs[PAR][KH][0][0] + tid16; \
        const __bf16* g_ = Bg + (long)(KT) * 64 + (KH) * 32; \
        gload16(g_, l_); \
        gload16(g_ + ldb128, l_ + 8192); }
#define VMC4 asm volatile("s_waitcnt vmcnt(4)" ::: "memory")
#define VMC0 asm volatile("s_waitcnt vmcnt(0)" ::: "memory")
#define BAR  __builtin_amdgcn_s_barrier()
#define RD_A(IDX, PAR, KS, MH) { \
        const char* a_ = (const char*)&As[PAR][KS][0][0]; \
        _Pragma("unroll") \
        for (int m_ = 0; m_ < 4; ++m_) { \
            int r_ = wm * 128 + (MH) * 64 + m_ * 16 + fr; \
            af[IDX][m_] = *(const bf16x8*)(a_ + (((r_ << 6) + gb) ^ ((r_ & 7) << 4))); } }
#define RD_B(IDX, PAR, KS) { \
        const char* b_ = (const char*)&Bs[PAR][KS][0][0]; \
        _Pragma("unroll") \
        for (int n_ = 0; n_ < 4; ++n_) { \
            int r_ = wn * 64 + n_ * 16 + fr; \
            bfr[IDX][n_] = *(const bf16x8*)(b_ + (((r_ << 6) + gb) ^ ((r_ & 7) << 4))); } }
#define MFMA16(AC, BC, MH) { \
        __builtin_amdgcn_s_setprio(1); \
        _Pragma("unroll") \
        for (int m_ = 0; m_ < 4; ++m_) { \
            _Pragma("unroll") \
            for (int n_ = 0; n_ < 4; ++n_) \
                acc[(MH) * 4 + m_][n_] = __builtin_amdgcn_mfma_f32_16x16x32_bf16( \
                    af[AC][m_], bfr[BC][n_], acc[(MH) * 4 + m_][n_], 0, 0, 0); } \
        __builtin_amdgcn_s_setprio(0); }

    // prologue: stage t0 fully + t1.{B0,A0,B1}; vmcnt(4) -> t0 resident; then
    // initial RA for P1 (frags from parity0/ks0).
    STAGE_B(0, 0, 0); STAGE_A(0, 0, 0); STAGE_B(0, 0, 1); STAGE_A(0, 0, 1);
    STAGE_B(1, 1, 0); STAGE_A(1, 1, 0); STAGE_B(1, 1, 1);
    VMC4;
    BAR;
    RD_B(0, 0, 0); RD_A(0, 0, 0, 0);

    for (int I = 0; I < NI; ++I) {
        const int t = 2 * I;
        const bool nl = (I < NI - 1);
        // P1: use (par0,ks0,mh0) frags af0/bfr0; RA af1 <- A[0][0] mh1
        STAGE_A(1, t + 1, 1);
        BAR; RD_A(1, 0, 0, 1);            MFMA16(0, 0, 0); BAR;
        // P2: use mh1 af1/bfr0; RA bfr1 <- B[0][1], af0 <- A[0][1] mh0
        if (nl) STAGE_B(0, t + 2, 0);
        BAR; RD_B(1, 0, 1); RD_A(0, 0, 1, 0); MFMA16(1, 0, 1); BAR;
        // P3: use (par0,ks1,mh0) af0/bfr1; RA af1 <- A[0][1] mh1
        if (nl) STAGE_A(0, t + 2, 0);
        BAR; RD_A(1, 0, 1, 1);            MFMA16(0, 1, 0); BAR;
        // P4: use mh1 af1/bfr1; RA bfr0 <- B[1][0], af0 <- A[1][0] mh0
        if (nl) { STAGE_B(0, t + 2, 1); VMC4; } else { VMC0; }
        BAR; RD_B(0, 1, 0); RD_A(0, 1, 0, 0); MFMA16(1, 1, 1); BAR;
        // P5: use (par1,ks0,mh0) af0/bfr0; RA af1 <- A[1][0] mh1
        if (nl) STAGE_A(0, t + 2, 1);
        BAR; RD_A(1, 1, 0, 1);            MFMA16(0, 0, 0); BAR;
        // P6: use mh1 af1/bfr0; RA bfr1 <- B[1][1], af0 <- A[1][1] mh0
        if (nl) STAGE_B(1, t + 3, 0);
        BAR; RD_B(1, 1, 1); RD_A(0, 1, 1, 0); MFMA16(1, 0, 1); BAR;
        // P7: use (par1,ks1,mh0) af0/bfr1; RA af1 <- A[1][1] mh1
        if (nl) STAGE_A(1, t + 3, 0);
        BAR; RD_A(1, 1, 1, 1);            MFMA16(0, 1, 0); BAR;
        // P8: use mh1 af1/bfr1; RA bfr0 <- B[0][0](t+2), af0 <- A[0][0](t+2) mh0
        if (nl) { STAGE_B(1, t + 3, 1); VMC4; }
        BAR; RD_B(0, 0, 0); RD_A(0, 0, 0, 0); MFMA16(1, 1, 1); BAR;
    }
#undef MFMA16
#undef RD_B
#undef RD_A
#undef BAR
#undef VMC0
#undef VMC4
#undef STAGE_B
#undef STAGE_A

    // epilogue: D row = (lane>>4)*4 + r, col = lane&15 per 16x16 frag
    const int r0q = (lane >> 4) << 2;
    #pragma unroll
    for (int n = 0; n < 4; ++n) {
        const int gc = n0 + wn * 64 + n * 16 + fr;
        const float bval = bias ? bias[gc] : 0.0f;
        #pragma unroll
        for (int mq = 0; mq < 8; ++mq) {
            const long rbase = (long)(m0 + wm * 128 + mq * 16 + r0q);
            #pragma unroll
            for (int r = 0; r < 4; ++r) {
                float v = acc[mq][n][r] + bval;
                const long row = rbase + r;
                if (MODE == 1) {
                    // tanh-form GELU (<=3e-4 abs err; overflow-safe via |u|)
                    float u = v * (0.7978845608f + 0.0356774081f * v * v);
                    float e = __expf(-2.0f * fabsf(u));
                    float th = (1.0f - e) / (1.0f + e);
                    th = copysignf(th, u);
                    v = 0.5f * v * (1.0f + th);
                    ((__bf16*)Cv)[row * ldc + gc] = (__bf16)v;
                } else {
                    ((float*)Cv)[row * ldc + gc] = v;
                }
            }
        }
    }
}

// ---------------- host ----------------
extern "C" void kernel_launch(void* const* d_in, const int* in_sizes, int n_in,
                              void* d_out, int out_size, void* d_ws, size_t ws_size,
                              hipStream_t stream) {
    constexpr int Bsz = 16384, F = 1024, GD = 512, TD = 768;
    constexpr int XLD = F + GD + TD;  // 2304

    const float* gnn = (const float*)d_in[0];
    const float* tr  = (const float*)d_in[1];
    const float* Wg  = (const float*)d_in[2];
    const float* bg  = (const float*)d_in[3];
    const float* Wt  = (const float*)d_in[4];
    const float* bt  = (const float*)d_in[5];
    const float* Wv  = (const float*)d_in[6];
    const float* bv  = (const float*)d_in[7];
    const float* Wo  = (const float*)d_in[8];
    const float* bo  = (const float*)d_in[9];
    const float* W1  = (const float*)d_in[10];
    const float* b1  = (const float*)d_in[11];
    const float* W2  = (const float*)d_in[12];
    const float* b2  = (const float*)d_in[13];
    float* out = (float*)d_out;

    char* w = (char*)d_ws;
    auto alloc = [&](size_t bytes) {
        char* p = w;
        w += (bytes + 255) & ~(size_t)255;
        return p;
    };
    __bf16* X    = (__bf16*)alloc((size_t)Bsz * XLD * 2);       // [h | gnn | tr]
    __bf16* M1   = (__bf16*)alloc((size_t)F * (GD + TD) * 2);   // [Mg | Mt]
    __bf16* Wp   = (__bf16*)alloc((size_t)F * XLD * 2);         // [W2 | Wg | Wt]
    __bf16* WvT  = (__bf16*)alloc((size_t)F * F * 2);
    __bf16* WgT  = (__bf16*)alloc((size_t)GD * F * 2);
    __bf16* WtT  = (__bf16*)alloc((size_t)TD * F * 2);
    __bf16* Wo_b = (__bf16*)alloc((size_t)F * F * 2);
    __bf16* W1ab = (__bf16*)alloc((size_t)2 * F * F * 2);       // [W1a ; W1b]
    __bf16* AT   = (__bf16*)alloc((size_t)F * F * 2);
    __bf16* PQ   = (__bf16*)alloc((size_t)2 * F * F * 2);       // [P ; Q]
    float* b_att = (float*)alloc(F * 4);
    float* bz2   = (float*)alloc(F * 4);
    float* b_out = (float*)alloc(F * 4);
    if ((size_t)(w - (char*)d_ws) > ws_size) return;

    dim3 b256(256);
    __bf16* P = PQ;
    __bf16* Q = PQ + (size_t)F * F;

    k_prep_convert<<<dim3(12928), b256, 0, stream>>>(gnn, tr, Wo, W1, W2, Wg, Wt,
                                                     X, Wo_b, W1ab, Wp);
    k_prep_transpose<<<dim3(2304), dim3(32, 8), 0, stream>>>(Wv, Wg, Wt, WvT, WgT, WtT);
    k_bias_att<<<dim3(F), b256, 0, stream>>>(Wo, bv, bo, b_att);

    // weight-composition GEMMs
    k_gemm_nt<64, 64><<<dim3((F / 64) * (F / 64)), b256, 0, stream>>>(
        WvT, F, Wo_b, F, AT, F, F, F / 64);
    k_gemm_nt<64, 64><<<dim3((2 * F / 64) * (F / 64)), b256, 0, stream>>>(
        W1ab, F, AT, F, PQ, F, F, F / 64);
    k_gemm_nt<64, 64><<<dim3((F / 64) * (GD / 64)), b256, 0, stream>>>(
        Q, F, WgT, F, M1, GD + TD, F, GD / 64);
    k_gemm_nt<64, 64><<<dim3((F / 64) * (TD / 64)), b256, 0, stream>>>(
        P, F, WtT, F, M1 + GD, GD + TD, F, TD / 64);

    k_bias_z2<<<dim3(F), b256, 0, stream>>>(W1, b_att, b1, P, Q, bt, bg, b2, bz2, b_out);

    // pass 1: h = gelu([gnn|tr] @ M1^T + bz2) -> X[:, 0:1024] (bf16)   K=1280
    k_gemm8<1><<<dim3((Bsz / 256) * (F / 256)), dim3(512), 0, stream>>>(
        X + F, XLD, M1, GD + TD, X, XLD, bz2, GD + TD, F / 256);

    // pass 2: out = [h|gnn|tr] @ [W2|Wg|Wt]^T + b_out (fp32)           K=2304
    k_gemm8<2><<<dim3((Bsz / 256) * (F / 256)), dim3(512), 0, stream>>>(
        X, XLD, Wp, XLD, out, F, b_out, XLD, F / 256);
}

// Round 5
// 232.987 us; speedup vs baseline: 1.0019x; 1.0019x over previous
//
#include <hip/hip_runtime.h>
#include <cmath>

#define GAS __attribute__((address_space(1)))
#define LAS __attribute__((address_space(3)))

typedef __bf16 bf16x8 __attribute__((ext_vector_type(8)));
typedef float f32x4 __attribute__((ext_vector_type(4)));

__device__ __forceinline__ void gload16(const void* g, void* l) {
    __builtin_amdgcn_global_load_lds((const GAS void*)g, (LAS void*)l, 16, 0, 0);
}

// ---------------- merged fp32 -> bf16 converts (8 elems / thread) ----------------
__global__ void k_prep_convert(const float* __restrict__ gnn, const float* __restrict__ tr,
                               const float* __restrict__ Wo, const float* __restrict__ W1,
                               const float* __restrict__ W2, const float* __restrict__ Wg,
                               const float* __restrict__ Wt,
                               __bf16* __restrict__ X, __bf16* __restrict__ Wo_b,
                               __bf16* __restrict__ W1ab, __bf16* __restrict__ Wp) {
    int b = blockIdx.x;
    const float* src; __bf16* dst; int sld, dld, base, c8;
    if (b < 4096)       { src = gnn;       sld = 512;  dst = X + 1024;        dld = 2304; base = 0;     c8 = 64; }
    else if (b < 10240) { src = tr;        sld = 768;  dst = X + 1536;        dld = 2304; base = 4096;  c8 = 96; }
    else if (b < 10752) { src = Wo;        sld = 1024; dst = Wo_b;            dld = 1024; base = 10240; c8 = 128; }
    else if (b < 11264) { src = W1;        sld = 2048; dst = W1ab;            dld = 1024; base = 10752; c8 = 128; }
    else if (b < 11776) { src = W1 + 1024; sld = 2048; dst = W1ab + 1024*1024; dld = 1024; base = 11264; c8 = 128; }
    else if (b < 12288) { src = W2;        sld = 1024; dst = Wp;              dld = 2304; base = 11776; c8 = 128; }
    else if (b < 12544) { src = Wg;        sld = 512;  dst = Wp + 1024;       dld = 2304; base = 12288; c8 = 64; }
    else                { src = Wt;        sld = 768;  dst = Wp + 1536;       dld = 2304; base = 12544; c8 = 96; }
    int idx = (b - base) * 256 + threadIdx.x;
    int r = idx / c8;
    int c = (idx - r * c8) << 3;
    const float4* s = reinterpret_cast<const float4*>(src + (long)r * sld + c);
    float4 x0 = s[0], x1 = s[1];
    bf16x8 v;
    v[0] = (__bf16)x0.x; v[1] = (__bf16)x0.y; v[2] = (__bf16)x0.z; v[3] = (__bf16)x0.w;
    v[4] = (__bf16)x1.x; v[5] = (__bf16)x1.y; v[6] = (__bf16)x1.z; v[7] = (__bf16)x1.w;
    *reinterpret_cast<bf16x8*>(dst + (long)r * dld + c) = v;
}

// ---------------- merged fp32 [R][C] -> bf16 [C][R] transposes ----------------
__global__ void k_prep_transpose(const float* __restrict__ Wv, const float* __restrict__ Wg,
                                 const float* __restrict__ Wt,
                                 __bf16* __restrict__ WvT, __bf16* __restrict__ WgT,
                                 __bf16* __restrict__ WtT) {
    __shared__ float t[32][33];
    int b = blockIdx.x;
    const float* src; __bf16* dst; int R, C, tile;
    if (b < 1024)      { src = Wv; dst = WvT; R = 1024; C = 1024; tile = b; }
    else if (b < 1536) { src = Wg; dst = WgT; R = 1024; C = 512;  tile = b - 1024; }
    else               { src = Wt; dst = WtT; R = 1024; C = 768;  tile = b - 1536; }
    int tx_n = C >> 5;
    int c0 = (tile % tx_n) << 5, r0 = (tile / tx_n) << 5;
    int tx = threadIdx.x, ty = threadIdx.y;  // 32 x 8
    #pragma unroll
    for (int i = 0; i < 32; i += 8)
        t[ty + i][tx] = src[(long)(r0 + ty + i) * C + c0 + tx];
    __syncthreads();
    #pragma unroll
    for (int i = 0; i < 32; i += 8)
        dst[(long)(c0 + ty + i) * R + r0 + tx] = (__bf16)t[tx][ty + i];
}

// ---------------- bias helpers ----------------
__global__ void k_bias_att(const float* __restrict__ Wo, const float* __restrict__ bv,
                           const float* __restrict__ bo, float* __restrict__ b_att) {
    int i = blockIdx.x;
    float s = 0.f;
    for (int k = threadIdx.x; k < 1024; k += 256) s += Wo[i * 1024 + k] * bv[k];
    __shared__ float red[256];
    red[threadIdx.x] = s;
    __syncthreads();
    for (int off = 128; off > 0; off >>= 1) {
        if (threadIdx.x < off) red[threadIdx.x] += red[threadIdx.x + off];
        __syncthreads();
    }
    if (threadIdx.x == 0) b_att[i] = red[0] + bo[i];
}

__global__ void k_bias_z2(const float* __restrict__ W1, const float* __restrict__ b_att,
                          const float* __restrict__ b1,
                          const __bf16* __restrict__ P, const __bf16* __restrict__ Q,
                          const float* __restrict__ bt, const float* __restrict__ bg,
                          const float* __restrict__ b2,
                          float* __restrict__ bz2, float* __restrict__ b_out) {
    int i = blockIdx.x;
    float s = 0.f;
    for (int k = threadIdx.x; k < 1024; k += 256) {
        s += (W1[(long)i * 2048 + k] + W1[(long)i * 2048 + 1024 + k]) * b_att[k];
        s += (float)P[i * 1024 + k] * bt[k];
        s += (float)Q[i * 1024 + k] * bg[k];
    }
    __shared__ float red[256];
    red[threadIdx.x] = s;
    __syncthreads();
    for (int off = 128; off > 0; off >>= 1) {
        if (threadIdx.x < off) red[threadIdx.x] += red[threadIdx.x + off];
        __syncthreads();
    }
    if (threadIdx.x == 0) {
        bz2[i] = red[0] + b1[i];
        b_out[i] = b2[i] + bg[i] + bt[i];
    }
}

// ---------------- small NT GEMM (64x64 tiles, 2-phase, verified) ----------------
template <int BM, int BN>
__global__ __launch_bounds__(256, 2) void k_gemm_nt(
    const __bf16* __restrict__ A, int lda,
    const __bf16* __restrict__ B, int ldb,
    __bf16* __restrict__ C, int ldc,
    int K, int n_tiles) {
    constexpr int BK = 32;
    constexpr int MR = BM / 32, NR = BN / 32;
    __shared__ alignas(16) __bf16 As[2][BM][BK];
    __shared__ alignas(16) __bf16 Bs[2][BN][BK];

    const int tid = threadIdx.x;
    const int lane = tid & 63;
    const int wave = tid >> 6;
    int bid = blockIdx.x;
    const int nwg = gridDim.x;
    if ((nwg & 7) == 0) bid = (bid & 7) * (nwg >> 3) + (bid >> 3);
    const int bn = bid % n_tiles;
    const int bm = bid / n_tiles;
    const int m0 = bm * BM, n0 = bn * BN;

    const int rp_l = tid >> 2;
    const int sp = tid & 3;

    const int wr = (wave >> 1) * (BM / 2);
    const int wc = (wave & 1) * (BN / 2);
    const int fr = lane & 15;
    const int fb = (lane >> 4) << 4;

    f32x4 acc[MR][NR] = {};
    const int nk = K / BK;

    auto stage = [&](int buf, int kt) {
        char* abase = (char*)&As[buf][0][0];
        char* bbase = (char*)&Bs[buf][0][0];
        #pragma unroll
        for (int it = 0; it < BM / 64; ++it) {
            int rp = it * 64 + rp_l;
            int rl = (rp & ~1) | ((rp ^ (rp >> 2)) & 1);
            int sl = sp ^ (rl & 3);
            gload16(A + (long)(m0 + rl) * lda + kt * BK + sl * 8,
                    abase + it * 4096 + tid * 16);
        }
        #pragma unroll
        for (int it = 0; it < BN / 64; ++it) {
            int rp = it * 64 + rp_l;
            int rl = (rp & ~1) | ((rp ^ (rp >> 2)) & 1);
            int sl = sp ^ (rl & 3);
            gload16(B + (long)(n0 + rl) * ldb + kt * BK + sl * 8,
                    bbase + it * 4096 + tid * 16);
        }
    };

    stage(0, 0);
    for (int kt = 0; kt < nk; ++kt) {
        const int buf = kt & 1;
        __syncthreads();
        if (kt + 1 < nk) stage(buf ^ 1, kt + 1);
        const char* abase = (const char*)&As[buf][0][0];
        const char* bbase = (const char*)&Bs[buf][0][0];
        bf16x8 af[MR], bfr[NR];
        #pragma unroll
        for (int m = 0; m < MR; ++m) {
            int r = wr + m * 16 + fr;
            af[m] = *(const bf16x8*)(abase + (((r << 6) + fb) ^ ((r & 7) << 4)));
        }
        #pragma unroll
        for (int n = 0; n < NR; ++n) {
            int r = wc + n * 16 + fr;
            bfr[n] = *(const bf16x8*)(bbase + (((r << 6) + fb) ^ ((r & 7) << 4)));
        }
        #pragma unroll
        for (int m = 0; m < MR; ++m)
            #pragma unroll
            for (int n = 0; n < NR; ++n)
                acc[m][n] = __builtin_amdgcn_mfma_f32_16x16x32_bf16(af[m], bfr[n], acc[m][n], 0, 0, 0);
    }

    const int r0 = (lane >> 4) << 2;
    #pragma unroll
    for (int n = 0; n < NR; ++n) {
        const int gc = n0 + wc + n * 16 + fr;
        #pragma unroll
        for (int m = 0; m < MR; ++m) {
            const long rbase = (long)(m0 + wr + m * 16 + r0);
            #pragma unroll
            for (int r = 0; r < 4; ++r)
                C[(rbase + r) * ldc + gc] = (__bf16)acc[m][n][r];
        }
    }
}

// ------------- 8-phase 256x256 NT GEMM, pinned register read-ahead --------------
// Phase = {stage; [vmcnt(6)]; barrier; PIN; RA ds_reads (frags for NEXT phase);
//          PIN; setprio; 16 MFMA on PREVIOUS phase's frags; setprio; barrier}.
// sched_barrier(0) pins stop hipcc from sinking the RA ds_reads across the raw
// s_barriers to their consumer (which re-serializes LDS drain and MFMA — the
// r3/r4 33% plateau). vmcnt(6) = 3 stages in flight (ledger verified: each RA
// target is staged >=3 stage-slots before its covering drain).
template <int MODE>
__device__ __forceinline__ void gemm8_body(
    const __bf16* __restrict__ A, int lda,
    const __bf16* __restrict__ B, int ldb,
    void* __restrict__ Cv, int ldc,
    const float* __restrict__ bias,
    int K, int n_tiles) {
    __shared__ __bf16 As[2][2][256][32];
    __shared__ __bf16 Bs[2][2][256][32];

    const int tid = threadIdx.x;
    const int lane = tid & 63;
    const int wave = tid >> 6;
    const int wm = wave >> 2;   // 0..1 -> 128 M-rows
    const int wn = wave & 3;    // 0..3 -> 64 N-cols

    int bid = blockIdx.x;
    const int nwg = gridDim.x;
    if ((nwg & 7) == 0) bid = (bid & 7) * (nwg >> 3) + (bid >> 3);
    const int bn = bid % n_tiles;
    const int bm = bid / n_tiles;
    const int m0 = bm * 256, n0 = bn * 256;

    // staging precompute (inverse swizzle, r2-verified)
    const int rp0 = tid >> 2;                              // 0..127
    const int rl0 = (rp0 & ~1) | ((rp0 ^ (rp0 >> 2)) & 1); // logical row
    const int slo = (tid & 3) ^ (rl0 & 3);                 // logical 16B slot
    const __bf16* Ag = A + (long)(m0 + rl0) * lda + slo * 8;
    const __bf16* Bg = B + (long)(n0 + rl0) * ldb + slo * 8;
    const long lda128 = (long)128 * lda;
    const long ldb128 = (long)128 * ldb;
    const int tid16 = tid * 16;

    const int fr = lane & 15;
    const int gb = (lane >> 4) << 4;

    f32x4 acc[8][4] = {};
    bf16x8 af[2][4];    // A-frag double buffer
    bf16x8 bfr[2][4];   // B-frag double buffer

    const int nk = K >> 6;
    const int NI = nk >> 1;

#define STAGE_A(PAR, KT, KH) { \
        char* l_ = (char*)&As[PAR][KH][0][0] + tid16; \
        const __bf16* g_ = Ag + (long)(KT) * 64 + (KH) * 32; \
        gload16(g_, l_); \
        gload16(g_ + lda128, l_ + 8192); }
#define STAGE_B(PAR, KT, KH) { \
        char* l_ = (char*)&Bs[PAR][KH][0][0] + tid16; \
        const __bf16* g_ = Bg + (long)(KT) * 64 + (KH) * 32; \
        gload16(g_, l_); \
        gload16(g_ + ldb128, l_ + 8192); }
#define VMC6 asm volatile("s_waitcnt vmcnt(6)" ::: "memory")
#define VMC4 asm volatile("s_waitcnt vmcnt(4)" ::: "memory")
#define VMC0 asm volatile("s_waitcnt vmcnt(0)" ::: "memory")
#define BAR  __builtin_amdgcn_s_barrier()
#define PIN  __builtin_amdgcn_sched_barrier(0)
#define RD_A(IDX, PAR, KS, MH) { \
        const char* a_ = (const char*)&As[PAR][KS][0][0]; \
        _Pragma("unroll") \
        for (int m_ = 0; m_ < 4; ++m_) { \
            int r_ = wm * 128 + (MH) * 64 + m_ * 16 + fr; \
            af[IDX][m_] = *(const bf16x8*)(a_ + (((r_ << 6) + gb) ^ ((r_ & 7) << 4))); } }
#define RD_B(IDX, PAR, KS) { \
        const char* b_ = (const char*)&Bs[PAR][KS][0][0]; \
        _Pragma("unroll") \
        for (int n_ = 0; n_ < 4; ++n_) { \
            int r_ = wn * 64 + n_ * 16 + fr; \
            bfr[IDX][n_] = *(const bf16x8*)(b_ + (((r_ << 6) + gb) ^ ((r_ & 7) << 4))); } }
#define MFMA16(AC, BC, MH) { \
        __builtin_amdgcn_s_setprio(1); \
        _Pragma("unroll") \
        for (int m_ = 0; m_ < 4; ++m_) { \
            _Pragma("unroll") \
            for (int n_ = 0; n_ < 4; ++n_) \
                acc[(MH) * 4 + m_][n_] = __builtin_amdgcn_mfma_f32_16x16x32_bf16( \
                    af[AC][m_], bfr[BC][n_], acc[(MH) * 4 + m_][n_], 0, 0, 0); } \
        __builtin_amdgcn_s_setprio(0); }

    // prologue: stage t0 fully + t1.{B0,A0,B1}; vmcnt(4) -> t0 resident; then
    // initial RA for P1 (frags from parity0/ks0).
    STAGE_B(0, 0, 0); STAGE_A(0, 0, 0); STAGE_B(0, 0, 1); STAGE_A(0, 0, 1);
    STAGE_B(1, 1, 0); STAGE_A(1, 1, 0); STAGE_B(1, 1, 1);
    VMC4;
    BAR;
    RD_B(0, 0, 0); RD_A(0, 0, 0, 0);

    for (int I = 0; I < NI; ++I) {
        const int t = 2 * I;
        const bool nl = (I < NI - 1);
        // P1: MFMA (par0,ks0,mh0) af0/bfr0; RA af1 <- A[0][0] mh1
        STAGE_A(1, t + 1, 1);
        BAR; PIN; RD_A(1, 0, 0, 1); PIN;            MFMA16(0, 0, 0); BAR;
        // P2: MFMA mh1 af1/bfr0; RA bfr1 <- B[0][1], af0 <- A[0][1] mh0
        if (nl) STAGE_B(0, t + 2, 0);
        BAR; PIN; RD_B(1, 0, 1); RD_A(0, 0, 1, 0); PIN; MFMA16(1, 0, 1); BAR;
        // P3: MFMA (par0,ks1,mh0) af0/bfr1; RA af1 <- A[0][1] mh1
        if (nl) STAGE_A(0, t + 2, 0);
        BAR; PIN; RD_A(1, 0, 1, 1); PIN;            MFMA16(0, 1, 0); BAR;
        // P4: MFMA mh1 af1/bfr1; RA bfr0 <- B[1][0], af0 <- A[1][0] mh0
        if (nl) { STAGE_B(0, t + 2, 1); VMC6; } else { VMC0; }
        BAR; PIN; RD_B(0, 1, 0); RD_A(0, 1, 0, 0); PIN; MFMA16(1, 1, 1); BAR;
        // P5: MFMA (par1,ks0,mh0) af0/bfr0; RA af1 <- A[1][0] mh1
        if (nl) STAGE_A(0, t + 2, 1);
        BAR; PIN; RD_A(1, 1, 0, 1); PIN;            MFMA16(0, 0, 0); BAR;
        // P6: MFMA mh1 af1/bfr0; RA bfr1 <- B[1][1], af0 <- A[1][1] mh0
        if (nl) STAGE_B(1, t + 3, 0);
        BAR; PIN; RD_B(1, 1, 1); RD_A(0, 1, 1, 0); PIN; MFMA16(1, 0, 1); BAR;
        // P7: MFMA (par1,ks1,mh0) af0/bfr1; RA af1 <- A[1][1] mh1
        if (nl) STAGE_A(1, t + 3, 0);
        BAR; PIN; RD_A(1, 1, 1, 1); PIN;            MFMA16(0, 1, 0); BAR;
        // P8: MFMA mh1 af1/bfr1; RA bfr0 <- B[0][0](t+2), af0 <- A[0][0](t+2) mh0
        if (nl) { STAGE_B(1, t + 3, 1); VMC6; }
        BAR; PIN; RD_B(0, 0, 0); RD_A(0, 0, 0, 0); PIN; MFMA16(1, 1, 1); BAR;
    }
#undef MFMA16
#undef RD_B
#undef RD_A
#undef PIN
#undef BAR
#undef VMC0
#undef VMC4
#undef VMC6
#undef STAGE_B
#undef STAGE_A

    // epilogue: D row = (lane>>4)*4 + r, col = lane&15 per 16x16 frag
    const int r0q = (lane >> 4) << 2;
    #pragma unroll
    for (int n = 0; n < 4; ++n) {
        const int gc = n0 + wn * 64 + n * 16 + fr;
        const float bval = bias ? bias[gc] : 0.0f;
        #pragma unroll
        for (int mq = 0; mq < 8; ++mq) {
            const long rbase = (long)(m0 + wm * 128 + mq * 16 + r0q);
            #pragma unroll
            for (int r = 0; r < 4; ++r) {
                float v = acc[mq][n][r] + bval;
                const long row = rbase + r;
                if (MODE == 1) {
                    // tanh-form GELU (<=3e-4 abs err; overflow-safe via |u|)
                    float u = v * (0.7978845608f + 0.0356774081f * v * v);
                    float e = __expf(-2.0f * fabsf(u));
                    float th = (1.0f - e) / (1.0f + e);
                    th = copysignf(th, u);
                    v = 0.5f * v * (1.0f + th);
                    ((__bf16*)Cv)[row * ldc + gc] = (__bf16)v;
                } else {
                    ((float*)Cv)[row * ldc + gc] = v;
                }
            }
        }
    }
}

// distinct names so rocprof attributes pass1 vs pass2 separately
__global__ __launch_bounds__(512, 2) void k_gemm8_gelu(
    const __bf16* __restrict__ A, int lda, const __bf16* __restrict__ B, int ldb,
    void* __restrict__ Cv, int ldc, const float* __restrict__ bias, int K, int n_tiles) {
    gemm8_body<1>(A, lda, B, ldb, Cv, ldc, bias, K, n_tiles);
}
__global__ __launch_bounds__(512, 2) void k_gemm8_out(
    const __bf16* __restrict__ A, int lda, const __bf16* __restrict__ B, int ldb,
    void* __restrict__ Cv, int ldc, const float* __restrict__ bias, int K, int n_tiles) {
    gemm8_body<2>(A, lda, B, ldb, Cv, ldc, bias, K, n_tiles);
}

// ---------------- host ----------------
extern "C" void kernel_launch(void* const* d_in, const int* in_sizes, int n_in,
                              void* d_out, int out_size, void* d_ws, size_t ws_size,
                              hipStream_t stream) {
    constexpr int Bsz = 16384, F = 1024, GD = 512, TD = 768;
    constexpr int XLD = F + GD + TD;  // 2304

    const float* gnn = (const float*)d_in[0];
    const float* tr  = (const float*)d_in[1];
    const float* Wg  = (const float*)d_in[2];
    const float* bg  = (const float*)d_in[3];
    const float* Wt  = (const float*)d_in[4];
    const float* bt  = (const float*)d_in[5];
    const float* Wv  = (const float*)d_in[6];
    const float* bv  = (const float*)d_in[7];
    const float* Wo  = (const float*)d_in[8];
    const float* bo  = (const float*)d_in[9];
    const float* W1  = (const float*)d_in[10];
    const float* b1  = (const float*)d_in[11];
    const float* W2  = (const float*)d_in[12];
    const float* b2  = (const float*)d_in[13];
    float* out = (float*)d_out;

    char* w = (char*)d_ws;
    auto alloc = [&](size_t bytes) {
        char* p = w;
        w += (bytes + 255) & ~(size_t)255;
        return p;
    };
    __bf16* X    = (__bf16*)alloc((size_t)Bsz * XLD * 2);       // [h | gnn | tr]
    __bf16* M1   = (__bf16*)alloc((size_t)F * (GD + TD) * 2);   // [Mg | Mt]
    __bf16* Wp   = (__bf16*)alloc((size_t)F * XLD * 2);         // [W2 | Wg | Wt]
    __bf16* WvT  = (__bf16*)alloc((size_t)F * F * 2);
    __bf16* WgT  = (__bf16*)alloc((size_t)GD * F * 2);
    __bf16* WtT  = (__bf16*)alloc((size_t)TD * F * 2);
    __bf16* Wo_b = (__bf16*)alloc((size_t)F * F * 2);
    __bf16* W1ab = (__bf16*)alloc((size_t)2 * F * F * 2);       // [W1a ; W1b]
    __bf16* AT   = (__bf16*)alloc((size_t)F * F * 2);
    __bf16* PQ   = (__bf16*)alloc((size_t)2 * F * F * 2);       // [P ; Q]
    float* b_att = (float*)alloc(F * 4);
    float* bz2   = (float*)alloc(F * 4);
    float* b_out = (float*)alloc(F * 4);
    if ((size_t)(w - (char*)d_ws) > ws_size) return;

    dim3 b256(256);
    __bf16* P = PQ;
    __bf16* Q = PQ + (size_t)F * F;

    k_prep_convert<<<dim3(12928), b256, 0, stream>>>(gnn, tr, Wo, W1, W2, Wg, Wt,
                                                     X, Wo_b, W1ab, Wp);
    k_prep_transpose<<<dim3(2304), dim3(32, 8), 0, stream>>>(Wv, Wg, Wt, WvT, WgT, WtT);
    k_bias_att<<<dim3(F), b256, 0, stream>>>(Wo, bv, bo, b_att);

    // weight-composition GEMMs
    k_gemm_nt<64, 64><<<dim3((F / 64) * (F / 64)), b256, 0, stream>>>(
        WvT, F, Wo_b, F, AT, F, F, F / 64);
    k_gemm_nt<64, 64><<<dim3((2 * F / 64) * (F / 64)), b256, 0, stream>>>(
        W1ab, F, AT, F, PQ, F, F, F / 64);
    k_gemm_nt<64, 64><<<dim3((F / 64) * (GD / 64)), b256, 0, stream>>>(
        Q, F, WgT, F, M1, GD + TD, F, GD / 64);
    k_gemm_nt<64, 64><<<dim3((F / 64) * (TD / 64)), b256, 0, stream>>>(
        P, F, WtT, F, M1 + GD, GD + TD, F, TD / 64);

    k_bias_z2<<<dim3(F), b256, 0, stream>>>(W1, b_att, b1, P, Q, bt, bg, b2, bz2, b_out);

    // pass 1: h = gelu([gnn|tr] @ M1^T + bz2) -> X[:, 0:1024] (bf16)   K=1280
    k_gemm8_gelu<<<dim3((Bsz / 256) * (F / 256)), dim3(512), 0, stream>>>(
        X + F, XLD, M1, GD + TD, X, XLD, bz2, GD + TD, F / 256);

    // pass 2: out = [h|gnn|tr] @ [W2|Wg|Wt]^T + b_out (fp32)           K=2304
    k_gemm8_out<<<dim3((Bsz / 256) * (F / 256)), dim3(512), 0, stream>>>(
        X, XLD, Wp, XLD, out, F, b_out, XLD, F / 256);
}

// Round 6
// 225.858 us; speedup vs baseline: 1.0335x; 1.0316x over previous
//
#include <hip/hip_runtime.h>
#include <cmath>

#define GAS __attribute__((address_space(1)))
#define LAS __attribute__((address_space(3)))

typedef __bf16 bf16x8 __attribute__((ext_vector_type(8)));
typedef float f32x4 __attribute__((ext_vector_type(4)));

__device__ __forceinline__ void gload16(const void* g, void* l) {
    __builtin_amdgcn_global_load_lds((const GAS void*)g, (LAS void*)l, 16, 0, 0);
}

// ---------------- merged fp32 -> bf16 converts (8 elems / thread) ----------------
__global__ void k_prep_convert(const float* __restrict__ gnn, const float* __restrict__ tr,
                               const float* __restrict__ Wo, const float* __restrict__ W1,
                               const float* __restrict__ W2, const float* __restrict__ Wg,
                               const float* __restrict__ Wt,
                               __bf16* __restrict__ X, __bf16* __restrict__ Wo_b,
                               __bf16* __restrict__ W1ab, __bf16* __restrict__ Wp) {
    int b = blockIdx.x;
    const float* src; __bf16* dst; int sld, dld, base, c8;
    if (b < 4096)       { src = gnn;       sld = 512;  dst = X + 1024;        dld = 2304; base = 0;     c8 = 64; }
    else if (b < 10240) { src = tr;        sld = 768;  dst = X + 1536;        dld = 2304; base = 4096;  c8 = 96; }
    else if (b < 10752) { src = Wo;        sld = 1024; dst = Wo_b;            dld = 1024; base = 10240; c8 = 128; }
    else if (b < 11264) { src = W1;        sld = 2048; dst = W1ab;            dld = 1024; base = 10752; c8 = 128; }
    else if (b < 11776) { src = W1 + 1024; sld = 2048; dst = W1ab + 1024*1024; dld = 1024; base = 11264; c8 = 128; }
    else if (b < 12288) { src = W2;        sld = 1024; dst = Wp;              dld = 2304; base = 11776; c8 = 128; }
    else if (b < 12544) { src = Wg;        sld = 512;  dst = Wp + 1024;       dld = 2304; base = 12288; c8 = 64; }
    else                { src = Wt;        sld = 768;  dst = Wp + 1536;       dld = 2304; base = 12544; c8 = 96; }
    int idx = (b - base) * 256 + threadIdx.x;
    int r = idx / c8;
    int c = (idx - r * c8) << 3;
    const float4* s = reinterpret_cast<const float4*>(src + (long)r * sld + c);
    float4 x0 = s[0], x1 = s[1];
    bf16x8 v;
    v[0] = (__bf16)x0.x; v[1] = (__bf16)x0.y; v[2] = (__bf16)x0.z; v[3] = (__bf16)x0.w;
    v[4] = (__bf16)x1.x; v[5] = (__bf16)x1.y; v[6] = (__bf16)x1.z; v[7] = (__bf16)x1.w;
    *reinterpret_cast<bf16x8*>(dst + (long)r * dld + c) = v;
}

// ---------------- merged fp32 [R][C] -> bf16 [C][R] transposes ----------------
__global__ void k_prep_transpose(const float* __restrict__ Wv, const float* __restrict__ Wg,
                                 const float* __restrict__ Wt,
                                 __bf16* __restrict__ WvT, __bf16* __restrict__ WgT,
                                 __bf16* __restrict__ WtT) {
    __shared__ float t[32][33];
    int b = blockIdx.x;
    const float* src; __bf16* dst; int R, C, tile;
    if (b < 1024)      { src = Wv; dst = WvT; R = 1024; C = 1024; tile = b; }
    else if (b < 1536) { src = Wg; dst = WgT; R = 1024; C = 512;  tile = b - 1024; }
    else               { src = Wt; dst = WtT; R = 1024; C = 768;  tile = b - 1536; }
    int tx_n = C >> 5;
    int c0 = (tile % tx_n) << 5, r0 = (tile / tx_n) << 5;
    int tx = threadIdx.x, ty = threadIdx.y;  // 32 x 8
    #pragma unroll
    for (int i = 0; i < 32; i += 8)
        t[ty + i][tx] = src[(long)(r0 + ty + i) * C + c0 + tx];
    __syncthreads();
    #pragma unroll
    for (int i = 0; i < 32; i += 8)
        dst[(long)(c0 + ty + i) * R + r0 + tx] = (__bf16)t[tx][ty + i];
}

// ---------------- bias helpers ----------------
__global__ void k_bias_att(const float* __restrict__ Wo, const float* __restrict__ bv,
                           const float* __restrict__ bo, float* __restrict__ b_att) {
    int i = blockIdx.x;
    float s = 0.f;
    for (int k = threadIdx.x; k < 1024; k += 256) s += Wo[i * 1024 + k] * bv[k];
    __shared__ float red[256];
    red[threadIdx.x] = s;
    __syncthreads();
    for (int off = 128; off > 0; off >>= 1) {
        if (threadIdx.x < off) red[threadIdx.x] += red[threadIdx.x + off];
        __syncthreads();
    }
    if (threadIdx.x == 0) b_att[i] = red[0] + bo[i];
}

__global__ void k_bias_z2(const float* __restrict__ W1, const float* __restrict__ b_att,
                          const float* __restrict__ b1,
                          const __bf16* __restrict__ P, const __bf16* __restrict__ Q,
                          const float* __restrict__ bt, const float* __restrict__ bg,
                          const float* __restrict__ b2,
                          float* __restrict__ bz2, float* __restrict__ b_out) {
    int i = blockIdx.x;
    float s = 0.f;
    for (int k = threadIdx.x; k < 1024; k += 256) {
        s += (W1[(long)i * 2048 + k] + W1[(long)i * 2048 + 1024 + k]) * b_att[k];
        s += (float)P[i * 1024 + k] * bt[k];
        s += (float)Q[i * 1024 + k] * bg[k];
    }
    __shared__ float red[256];
    red[threadIdx.x] = s;
    __syncthreads();
    for (int off = 128; off > 0; off >>= 1) {
        if (threadIdx.x < off) red[threadIdx.x] += red[threadIdx.x + off];
        __syncthreads();
    }
    if (threadIdx.x == 0) {
        bz2[i] = red[0] + b1[i];
        b_out[i] = b2[i] + bg[i] + bt[i];
    }
}

// ---------------- small NT GEMM (64x64 tiles, 2-phase, verified) ----------------
template <int BM, int BN>
__global__ __launch_bounds__(256, 2) void k_gemm_nt(
    const __bf16* __restrict__ A, int lda,
    const __bf16* __restrict__ B, int ldb,
    __bf16* __restrict__ C, int ldc,
    int K, int n_tiles) {
    constexpr int BK = 32;
    constexpr int MR = BM / 32, NR = BN / 32;
    __shared__ alignas(16) __bf16 As[2][BM][BK];
    __shared__ alignas(16) __bf16 Bs[2][BN][BK];

    const int tid = threadIdx.x;
    const int lane = tid & 63;
    const int wave = tid >> 6;
    int bid = blockIdx.x;
    const int nwg = gridDim.x;
    if ((nwg & 7) == 0) bid = (bid & 7) * (nwg >> 3) + (bid >> 3);
    const int bn = bid % n_tiles;
    const int bm = bid / n_tiles;
    const int m0 = bm * BM, n0 = bn * BN;

    const int rp_l = tid >> 2;
    const int sp = tid & 3;

    const int wr = (wave >> 1) * (BM / 2);
    const int wc = (wave & 1) * (BN / 2);
    const int fr = lane & 15;
    const int fb = (lane >> 4) << 4;

    f32x4 acc[MR][NR] = {};
    const int nk = K / BK;

    auto stage = [&](int buf, int kt) {
        char* abase = (char*)&As[buf][0][0];
        char* bbase = (char*)&Bs[buf][0][0];
        #pragma unroll
        for (int it = 0; it < BM / 64; ++it) {
            int rp = it * 64 + rp_l;
            int rl = (rp & ~1) | ((rp ^ (rp >> 2)) & 1);
            int sl = sp ^ (rl & 3);
            gload16(A + (long)(m0 + rl) * lda + kt * BK + sl * 8,
                    abase + it * 4096 + tid * 16);
        }
        #pragma unroll
        for (int it = 0; it < BN / 64; ++it) {
            int rp = it * 64 + rp_l;
            int rl = (rp & ~1) | ((rp ^ (rp >> 2)) & 1);
            int sl = sp ^ (rl & 3);
            gload16(B + (long)(n0 + rl) * ldb + kt * BK + sl * 8,
                    bbase + it * 4096 + tid * 16);
        }
    };

    stage(0, 0);
    for (int kt = 0; kt < nk; ++kt) {
        const int buf = kt & 1;
        __syncthreads();
        if (kt + 1 < nk) stage(buf ^ 1, kt + 1);
        const char* abase = (const char*)&As[buf][0][0];
        const char* bbase = (const char*)&Bs[buf][0][0];
        bf16x8 af[MR], bfr[NR];
        #pragma unroll
        for (int m = 0; m < MR; ++m) {
            int r = wr + m * 16 + fr;
            af[m] = *(const bf16x8*)(abase + (((r << 6) + fb) ^ ((r & 7) << 4)));
        }
        #pragma unroll
        for (int n = 0; n < NR; ++n) {
            int r = wc + n * 16 + fr;
            bfr[n] = *(const bf16x8*)(bbase + (((r << 6) + fb) ^ ((r & 7) << 4)));
        }
        #pragma unroll
        for (int m = 0; m < MR; ++m)
            #pragma unroll
            for (int n = 0; n < NR; ++n)
                acc[m][n] = __builtin_amdgcn_mfma_f32_16x16x32_bf16(af[m], bfr[n], acc[m][n], 0, 0, 0);
    }

    const int r0 = (lane >> 4) << 2;
    #pragma unroll
    for (int n = 0; n < NR; ++n) {
        const int gc = n0 + wc + n * 16 + fr;
        #pragma unroll
        for (int m = 0; m < MR; ++m) {
            const long rbase = (long)(m0 + wr + m * 16 + r0);
            #pragma unroll
            for (int r = 0; r < 4; ++r)
                C[(rbase + r) * ldc + gc] = (__bf16)acc[m][n][r];
        }
    }
}

// ---- 8-phase 256x256 NT GEMM, frag-major LDS (conflict-free by construction) ----
// LDS 128KB: A = [2 par][2 mh][2 qh][4 mq][2 kk][1KB frag], B at +64KB =
// [2 par][2 nh][2 kk][8 nfrag][1KB frag]. Every frag is a contiguous 1KB block:
// ds_read_b128 = contiguous 64-lane read (zero bank conflicts, any grouping);
// global_load_lds dest = linear tid*16 (required); the fragment permutation is
// applied on the per-thread GLOBAL source address (coalescing unchanged:
// 16 rows x 64B segments per wave-op). Stage unit = 8KB = 1 gload16.
// Phase order per K-tile: (q0,k0),(q0,k1),(q1,k0),(q1,k1); B-frags read at kk
// first-use, reused at q1. vmcnt ledger (verified): P1/P5 vmcnt(8), P2/P6
// vmcnt(6); stage slots placed right after each region's last reader.
// Epilogue: per-wave 16KB LDS scratch remap -> coalesced wide stores.
// MODE 1: +bias, GELU (tanh-form), bf16 out; MODE 2: +bias, fp32 out.
template <int MODE>
__device__ __forceinline__ void gemm8_body(
    const __bf16* __restrict__ A, int lda,
    const __bf16* __restrict__ B, int ldb,
    void* __restrict__ Cv, int ldc,
    const float* __restrict__ bias,
    int K, int n_tiles) {
    __shared__ char lds[131072];

    const int tid = threadIdx.x;
    const int lane = tid & 63;
    const int wave = tid >> 6;
    const int wm = wave >> 2;   // 0..1 -> 128 M-rows
    const int wn = wave & 3;    // 0..3 -> 64 N-cols

    int bid = blockIdx.x;
    const int nwg = gridDim.x;
    if ((nwg & 7) == 0) bid = (bid & 7) * (nwg >> 3) + (bid >> 3);
    const int bn = bid % n_tiles;
    const int bm = bid / n_tiles;
    const int m0 = bm * 256, n0 = bn * 256;

    // staging source map (frag-major): thread t fills dest byte t*16 of an 8KB
    // region. A region (mh,qh): mq_l=t>>7, kk=(t>>6)&1, fr=t&15, q=(t>>4)&3
    //   -> src row = mh*128+qh*64+mq_l*16+fr, col = kt*64 + kk*32 + q*8
    // B region (nh,kk): nfrag=t>>6 -> row = nh*128+nfrag*16+fr, col = kt*64+kk*32+q*8
    const int rowA = ((tid >> 7) << 4) + (tid & 15);
    const int colA = (((tid >> 6) & 1) << 5) + (((tid >> 4) & 3) << 3);
    const int rowB = ((tid >> 6) << 4) + (tid & 15);
    const int colB = (((tid >> 4) & 3) << 3);
    const __bf16* Ag = A + (long)(m0 + rowA) * lda + colA;
    const __bf16* Bg = B + (long)(n0 + rowB) * ldb + colB;
    const int tid16 = tid * 16;
    const int l16 = lane * 16;
    const int fr = lane & 15;

    const int bnh = wn >> 1;            // B half index
    const int bno = (wn & 1) * 4096;    // nfrag sub-offset

    f32x4 acc[8][4] = {};
    bf16x8 af[4];
    bf16x8 bfr[2][4];

    const int nk = K >> 6;
    const int NI = nk >> 1;

#define STAGE_A(PAR, KT, MH, QH) \
    gload16(Ag + (long)(KT) * 64 + (long)((MH) * 128 + (QH) * 64) * lda, \
            lds + (PAR) * 32768 + (MH) * 16384 + (QH) * 8192 + tid16)
#define STAGE_B(PAR, KT, NH, KK) \
    gload16(Bg + (long)(KT) * 64 + (KK) * 32 + (long)((NH) * 128) * ldb, \
            lds + 65536 + (PAR) * 32768 + (NH) * 16384 + (KK) * 8192 + tid16)
#define VMC8 asm volatile("s_waitcnt vmcnt(8)" ::: "memory")
#define VMC6 asm volatile("s_waitcnt vmcnt(6)" ::: "memory")
#define VMC0 asm volatile("s_waitcnt vmcnt(0)" ::: "memory")
#define BAR  __builtin_amdgcn_s_barrier()
#define RD_A4(PAR, QH, KK) { \
        const char* a_ = lds + (PAR) * 32768 + wm * 16384 + (QH) * 8192 + (KK) * 1024; \
        _Pragma("unroll") \
        for (int m_ = 0; m_ < 4; ++m_) \
            af[m_] = *(const bf16x8*)(a_ + m_ * 2048 + l16); }
#define RD_B4(KK, PAR) { \
        const char* b_ = lds + 65536 + (PAR) * 32768 + bnh * 16384 + (KK) * 8192 + bno; \
        _Pragma("unroll") \
        for (int n_ = 0; n_ < 4; ++n_) \
            bfr[KK][n_] = *(const bf16x8*)(b_ + n_ * 1024 + l16); }
#define MFMA16(QH, KK) { \
        __builtin_amdgcn_s_setprio(1); \
        _Pragma("unroll") \
        for (int m_ = 0; m_ < 4; ++m_) { \
            _Pragma("unroll") \
            for (int n_ = 0; n_ < 4; ++n_) \
                acc[(QH) * 4 + m_][n_] = __builtin_amdgcn_mfma_f32_16x16x32_bf16( \
                    af[m_], bfr[KK][n_], acc[(QH) * 4 + m_][n_], 0, 0, 0); } \
        __builtin_amdgcn_s_setprio(0); }

    // prologue: t0 {Aq0, Bk0, Aq1, Bk1}, t1 {Aq0, Bk0}  (12 gloads, order matters)
    STAGE_A(0, 0, 0, 0); STAGE_A(0, 0, 1, 0);
    STAGE_B(0, 0, 0, 0); STAGE_B(0, 0, 1, 0);
    STAGE_A(0, 0, 0, 1); STAGE_A(0, 0, 1, 1);
    STAGE_B(0, 0, 0, 1); STAGE_B(0, 0, 1, 1);
    STAGE_A(1, 1, 0, 0); STAGE_A(1, 1, 1, 0);
    STAGE_B(1, 1, 0, 0); STAGE_B(1, 1, 1, 0);

    for (int I = 0; I < NI; ++I) {
        const int t = 2 * I;
        const bool nl = (I + 1 < NI);
        // P1: tile t (par0), q0,k0
        VMC8;
        STAGE_A(1, t + 1, 0, 1); STAGE_A(1, t + 1, 1, 1);
        BAR; RD_B4(0, 0); RD_A4(0, 0, 0); MFMA16(0, 0); BAR;
        // P2: q0,k1
        VMC6;
        STAGE_B(1, t + 1, 0, 1); STAGE_B(1, t + 1, 1, 1);
        BAR; RD_B4(1, 0); RD_A4(0, 0, 1); MFMA16(0, 1); BAR;
        // P3: q1,k0
        if (nl) { STAGE_A(0, t + 2, 0, 0); STAGE_A(0, t + 2, 1, 0); } else { VMC0; }
        BAR; RD_A4(0, 1, 0); MFMA16(1, 0); BAR;
        // P4: q1,k1
        if (nl) { STAGE_B(0, t + 2, 0, 0); STAGE_B(0, t + 2, 1, 0); }
        BAR; RD_A4(0, 1, 1); MFMA16(1, 1); BAR;
        // P5: tile t+1 (par1), q0,k0
        VMC8;
        if (nl) { STAGE_A(0, t + 2, 0, 1); STAGE_A(0, t + 2, 1, 1); }
        BAR; RD_B4(0, 1); RD_A4(1, 0, 0); MFMA16(0, 0); BAR;
        // P6: q0,k1
        VMC6;
        if (nl) { STAGE_B(0, t + 2, 0, 1); STAGE_B(0, t + 2, 1, 1); }
        BAR; RD_B4(1, 1); RD_A4(1, 0, 1); MFMA16(0, 1); BAR;
        // P7: q1,k0
        if (nl) { STAGE_A(1, t + 3, 0, 0); STAGE_A(1, t + 3, 1, 0); }
        BAR; RD_A4(1, 1, 0); MFMA16(1, 0); BAR;
        // P8: q1,k1
        if (nl) { STAGE_B(1, t + 3, 0, 0); STAGE_B(1, t + 3, 1, 0); }
        BAR; RD_A4(1, 1, 1); MFMA16(1, 1); BAR;
    }
#undef MFMA16
#undef RD_B4
#undef RD_A4
#undef BAR
#undef VMC0
#undef VMC6
#undef VMC8
#undef STAGE_B
#undef STAGE_A

    // ---- epilogue: per-wave LDS remap (16KB scratch each) -> coalesced stores
    // frag layout: elem r -> row (lane>>4)*4+r, col lane&15 (m89-verified)
    char* scr = lds + wave * 16384;   // scratch rows: 272B stride (68 f32, 16B-aligned)
    float bval[4];
    #pragma unroll
    for (int n_ = 0; n_ < 4; ++n_)
        bval[n_] = bias ? bias[n0 + wn * 64 + n_ * 16 + fr] : 0.0f;
    const int r0q = (lane >> 4) << 2;

    #pragma unroll
    for (int mq = 0; mq < 8; ++mq) {
        #pragma unroll
        for (int n_ = 0; n_ < 4; ++n_) {
            #pragma unroll
            for (int r = 0; r < 4; ++r) {
                float v = acc[mq][n_][r] + bval[n_];
                if (MODE == 1) {
                    float u = v * (0.7978845608f + 0.0356774081f * v * v);
                    float e = __expf(-2.0f * fabsf(u));
                    float th = (1.0f - e) / (1.0f + e);
                    th = copysignf(th, u);
                    v = 0.5f * v * (1.0f + th);
                }
                *(float*)(scr + (r0q + r) * 272 + (n_ * 16 + fr) * 4) = v;
            }
        }
        __builtin_amdgcn_s_waitcnt(0);  // drain lgkm (scratch RAW, per-wave)
        if (MODE == 2) {
            #pragma unroll
            for (int rep = 0; rep < 4; ++rep) {
                int row = rep * 4 + (lane >> 4);
                f32x4 val = *(const f32x4*)(scr + row * 272 + (lane & 15) * 16);
                long grow = (long)(m0 + wm * 128 + mq * 16 + row);
                *(f32x4*)&((float*)Cv)[grow * ldc + n0 + wn * 64 + (lane & 15) * 4] = val;
            }
        } else {
            #pragma unroll
            for (int rep = 0; rep < 2; ++rep) {
                int row = rep * 8 + (lane >> 3);
                f32x4 v0 = *(const f32x4*)(scr + row * 272 + (lane & 7) * 32);
                f32x4 v1 = *(const f32x4*)(scr + row * 272 + (lane & 7) * 32 + 16);
                bf16x8 o;
                o[0] = (__bf16)v0[0]; o[1] = (__bf16)v0[1]; o[2] = (__bf16)v0[2]; o[3] = (__bf16)v0[3];
                o[4] = (__bf16)v1[0]; o[5] = (__bf16)v1[1]; o[6] = (__bf16)v1[2]; o[7] = (__bf16)v1[3];
                long grow = (long)(m0 + wm * 128 + mq * 16 + row);
                *(bf16x8*)&((__bf16*)Cv)[grow * ldc + n0 + wn * 64 + (lane & 7) * 8] = o;
            }
        }
        __builtin_amdgcn_s_waitcnt(0);  // scratch WAR before next mq overwrites
    }
}

// distinct names so rocprof attributes pass1 vs pass2 separately
__global__ __launch_bounds__(512, 2) void k_gemm8_gelu(
    const __bf16* __restrict__ A, int lda, const __bf16* __restrict__ B, int ldb,
    void* __restrict__ Cv, int ldc, const float* __restrict__ bias, int K, int n_tiles) {
    gemm8_body<1>(A, lda, B, ldb, Cv, ldc, bias, K, n_tiles);
}
__global__ __launch_bounds__(512, 2) void k_gemm8_out(
    const __bf16* __restrict__ A, int lda, const __bf16* __restrict__ B, int ldb,
    void* __restrict__ Cv, int ldc, const float* __restrict__ bias, int K, int n_tiles) {
    gemm8_body<2>(A, lda, B, ldb, Cv, ldc, bias, K, n_tiles);
}

// ---------------- host ----------------
extern "C" void kernel_launch(void* const* d_in, const int* in_sizes, int n_in,
                              void* d_out, int out_size, void* d_ws, size_t ws_size,
                              hipStream_t stream) {
    constexpr int Bsz = 16384, F = 1024, GD = 512, TD = 768;
    constexpr int XLD = F + GD + TD;  // 2304

    const float* gnn = (const float*)d_in[0];
    const float* tr  = (const float*)d_in[1];
    const float* Wg  = (const float*)d_in[2];
    const float* bg  = (const float*)d_in[3];
    const float* Wt  = (const float*)d_in[4];
    const float* bt  = (const float*)d_in[5];
    const float* Wv  = (const float*)d_in[6];
    const float* bv  = (const float*)d_in[7];
    const float* Wo  = (const float*)d_in[8];
    const float* bo  = (const float*)d_in[9];
    const float* W1  = (const float*)d_in[10];
    const float* b1  = (const float*)d_in[11];
    const float* W2  = (const float*)d_in[12];
    const float* b2  = (const float*)d_in[13];
    float* out = (float*)d_out;

    char* w = (char*)d_ws;
    auto alloc = [&](size_t bytes) {
        char* p = w;
        w += (bytes + 255) & ~(size_t)255;
        return p;
    };
    __bf16* X    = (__bf16*)alloc((size_t)Bsz * XLD * 2);       // [h | gnn | tr]
    __bf16* M1   = (__bf16*)alloc((size_t)F * (GD + TD) * 2);   // [Mg | Mt]
    __bf16* Wp   = (__bf16*)alloc((size_t)F * XLD * 2);         // [W2 | Wg | Wt]
    __bf16* WvT  = (__bf16*)alloc((size_t)F * F * 2);
    __bf16* WgT  = (__bf16*)alloc((size_t)GD * F * 2);
    __bf16* WtT  = (__bf16*)alloc((size_t)TD * F * 2);
    __bf16* Wo_b = (__bf16*)alloc((size_t)F * F * 2);
    __bf16* W1ab = (__bf16*)alloc((size_t)2 * F * F * 2);       // [W1a ; W1b]
    __bf16* AT   = (__bf16*)alloc((size_t)F * F * 2);
    __bf16* PQ   = (__bf16*)alloc((size_t)2 * F * F * 2);       // [P ; Q]
    float* b_att = (float*)alloc(F * 4);
    float* bz2   = (float*)alloc(F * 4);
    float* b_out = (float*)alloc(F * 4);
    if ((size_t)(w - (char*)d_ws) > ws_size) return;

    dim3 b256(256);
    __bf16* P = PQ;
    __bf16* Q = PQ + (size_t)F * F;

    k_prep_convert<<<dim3(12928), b256, 0, stream>>>(gnn, tr, Wo, W1, W2, Wg, Wt,
                                                     X, Wo_b, W1ab, Wp);
    k_prep_transpose<<<dim3(2304), dim3(32, 8), 0, stream>>>(Wv, Wg, Wt, WvT, WgT, WtT);
    k_bias_att<<<dim3(F), b256, 0, stream>>>(Wo, bv, bo, b_att);

    // weight-composition GEMMs
    k_gemm_nt<64, 64><<<dim3((F / 64) * (F / 64)), b256, 0, stream>>>(
        WvT, F, Wo_b, F, AT, F, F, F / 64);
    k_gemm_nt<64, 64><<<dim3((2 * F / 64) * (F / 64)), b256, 0, stream>>>(
        W1ab, F, AT, F, PQ, F, F, F / 64);
    k_gemm_nt<64, 64><<<dim3((F / 64) * (GD / 64)), b256, 0, stream>>>(
        Q, F, WgT, F, M1, GD + TD, F, GD / 64);
    k_gemm_nt<64, 64><<<dim3((F / 64) * (TD / 64)), b256, 0, stream>>>(
        P, F, WtT, F, M1 + GD, GD + TD, F, TD / 64);

    k_bias_z2<<<dim3(F), b256, 0, stream>>>(W1, b_att, b1, P, Q, bt, bg, b2, bz2, b_out);

    // pass 1: h = gelu([gnn|tr] @ M1^T + bz2) -> X[:, 0:1024] (bf16)   K=1280
    k_gemm8_gelu<<<dim3((Bsz / 256) * (F / 256)), dim3(512), 0, stream>>>(
        X + F, XLD, M1, GD + TD, X, XLD, bz2, GD + TD, F / 256);

    // pass 2: out = [h|gnn|tr] @ [W2|Wg|Wt]^T + b_out (fp32)           K=2304
    k_gemm8_out<<<dim3((Bsz / 256) * (F / 256)), dim3(512), 0, stream>>>(
        X, XLD, Wp, XLD, out, F, b_out, XLD, F / 256);
}